// Round 4
// baseline (407.446 us; speedup 1.0000x reference)
//
#include <hip/hip_runtime.h>

// TopKRouter: B=4,S=4096,D=4096,E=64,K=2 (tokens=16384)
// R8 (this round): direct-to-register MFMA pipeline (no main-loop LDS).
//   R4/R6 LDS-staged pipeline plateaued ~140us: 8 barrier-locked waves,
//   1 block/CU, in-flight capped by LDS (96 KB/CU). Depth scaling gave
//   diminishing returns (170 -> ~140us for depth 3->4).
//   R8 loads A-frags (8 contiguous fp32/lane, 2x dwordx4) and B-frags
//   (fragment-major wsg, 1KB/wave coalesced) straight into registers:
//   - no barriers, no LDS staging, waves fully independent (TLP hiding)
//   - 256-thr blocks (32 tok), ~130 VGPR -> 3-4 blocks/CU = 12-16 waves/CU
//   - 2-deep register ping-pong (A/B tile buffers, named fields: rule #20)
//   Cost: W re-read per eh-pair, x per tp-pair => ~1.5 GB L2 (~45us @34.5TB/s)
//   overlapped with 268 MB HBM x-stream (~43us). Floor ~50us.
//   Same numerics as R4 (split-bf16 3-MFMA), epilogue unchanged.

#define TOK 16384
#define DIM 4096
#define NE  64
#define BK  64
#define NT  (DIM / BK)           // 64 K-tiles
#define IDX_OFF (TOK * NE)
#define VAL_OFF (IDX_OFF + TOK * 2)

typedef __attribute__((ext_vector_type(8))) short short8;
typedef __attribute__((ext_vector_type(4))) float f32x4;
union pk8u { unsigned int u[4]; short8 s; };

__device__ __forceinline__ unsigned int pack_hi(float fa, float fb) {
    return __builtin_amdgcn_perm(__float_as_uint(fb), __float_as_uint(fa), 0x07060302u);
}
__device__ __forceinline__ unsigned int pack_lo(float fa, float fb) {
    float la = fa - __uint_as_float(__float_as_uint(fa) & 0xffff0000u);  // exact
    float lb = fb - __uint_as_float(__float_as_uint(fb) & 0xffff0000u);  // exact
    return __builtin_amdgcn_perm(__float_as_uint(lb), __float_as_uint(la), 0x07060302u);
}
__device__ __forceinline__ void split8(const float4 v0, const float4 v1,
                                       short8& hi, short8& lo) {
    pk8u h, l;
    h.u[0] = pack_hi(v0.x, v0.y); l.u[0] = pack_lo(v0.x, v0.y);
    h.u[1] = pack_hi(v0.z, v0.w); l.u[1] = pack_lo(v0.z, v0.w);
    h.u[2] = pack_hi(v1.x, v1.y); l.u[2] = pack_lo(v1.x, v1.y);
    h.u[3] = pack_hi(v1.z, v1.w); l.u[3] = pack_lo(v1.z, v1.w);
    hi = h.s; lo = l.s;
}

// W -> fragment-major packed bf16 hi/lo in ws. (unchanged from R4; verified)
// Unit layout: ws unit index r = t*16 + (c*8 + g*2 + h); within unit:
// lane l (0..63), 8 bf16 = W[e = g*16 + (l&15)][t*64 + c*32 + (l>>4)*8 + j]
__global__ __launch_bounds__(256)
void wconv_kernel(const float* __restrict__ W, unsigned short* __restrict__ ws) {
    const int gid = blockIdx.x * 256 + threadIdx.x;   // 0..65535
    const int l = gid & 63;
    const int r = gid >> 6;
    const int h = r & 1;
    const int g = (r >> 1) & 3;
    const int c = (r >> 3) & 1;
    const int t = r >> 4;                              // 0..63
    const int e = g * 16 + (l & 15);
    const int k = t * 64 + c * 32 + (l >> 4) * 8;
    const float4 va = *(const float4*)(W + (size_t)e * DIM + k);
    const float4 vb = *(const float4*)(W + (size_t)e * DIM + k + 4);
    pk8u o;
    if (h == 0) {                                      // wave-uniform branch
        o.u[0] = pack_hi(va.x, va.y); o.u[1] = pack_hi(va.z, va.w);
        o.u[2] = pack_hi(vb.x, vb.y); o.u[3] = pack_hi(vb.z, vb.w);
    } else {
        o.u[0] = pack_lo(va.x, va.y); o.u[1] = pack_lo(va.z, va.w);
        o.u[2] = pack_lo(vb.x, vb.y); o.u[3] = pack_lo(vb.z, vb.w);
    }
    ((uint4*)ws)[gid] = *(uint4*)&o.u[0];
}

// Per-tile register buffer. Named fields only (runtime-indexed ext_vector
// arrays go to scratch — guide rule #20).
struct TR {
    float4 x0, x1, x2, x3;                 // 8 fp32 for c=0, 8 for c=1
    short8 w0, w1, w2, w3, w4, w5, w6, w7; // (c,g2,h) B-frags, this wave's eh
};

// bx = x + token_row*DIM + q*8 ; bw = wsg + eh*2048 + lane*8
__device__ __forceinline__ void load_tile(TR& r, const float* bx,
                                          const unsigned short* bw, int t) {
    const float* px = bx + t * BK;
    r.x0 = *(const float4*)(px);            // c=0: k = q*8 .. +4
    r.x1 = *(const float4*)(px + 4);        //      k = q*8+4 .. +8
    r.x2 = *(const float4*)(px + 32);       // c=1
    r.x3 = *(const float4*)(px + 36);
    // unit u = (c*4 + eh*2 + g2)*2 + h ; short offset = t*8192 + u*512
    const unsigned short* pw = bw + (size_t)t * 8192;
    r.w0 = *(const short8*)(pw);            // c0 g2=0 h=0 (hi)
    r.w1 = *(const short8*)(pw + 512);      // c0 g2=0 h=1 (lo)
    r.w2 = *(const short8*)(pw + 1024);     // c0 g2=1 hi
    r.w3 = *(const short8*)(pw + 1536);     // c0 g2=1 lo
    r.w4 = *(const short8*)(pw + 4096);     // c1 g2=0 hi
    r.w5 = *(const short8*)(pw + 4608);     // c1 g2=0 lo
    r.w6 = *(const short8*)(pw + 5120);     // c1 g2=1 hi
    r.w7 = *(const short8*)(pw + 5632);     // c1 g2=1 lo
}

__device__ __forceinline__ void compute_tile(const TR& r, f32x4& acc0, f32x4& acc1) {
    short8 ah, al;
    split8(r.x0, r.x1, ah, al);            // c=0
    acc0 = __builtin_amdgcn_mfma_f32_16x16x32_bf16(ah, r.w0, acc0, 0, 0, 0);
    acc0 = __builtin_amdgcn_mfma_f32_16x16x32_bf16(al, r.w0, acc0, 0, 0, 0);
    acc0 = __builtin_amdgcn_mfma_f32_16x16x32_bf16(ah, r.w1, acc0, 0, 0, 0);
    acc1 = __builtin_amdgcn_mfma_f32_16x16x32_bf16(ah, r.w2, acc1, 0, 0, 0);
    acc1 = __builtin_amdgcn_mfma_f32_16x16x32_bf16(al, r.w2, acc1, 0, 0, 0);
    acc1 = __builtin_amdgcn_mfma_f32_16x16x32_bf16(ah, r.w3, acc1, 0, 0, 0);
    split8(r.x2, r.x3, ah, al);            // c=1
    acc0 = __builtin_amdgcn_mfma_f32_16x16x32_bf16(ah, r.w4, acc0, 0, 0, 0);
    acc0 = __builtin_amdgcn_mfma_f32_16x16x32_bf16(al, r.w4, acc0, 0, 0, 0);
    acc0 = __builtin_amdgcn_mfma_f32_16x16x32_bf16(ah, r.w5, acc0, 0, 0, 0);
    acc1 = __builtin_amdgcn_mfma_f32_16x16x32_bf16(ah, r.w6, acc1, 0, 0, 0);
    acc1 = __builtin_amdgcn_mfma_f32_16x16x32_bf16(al, r.w6, acc1, 0, 0, 0);
    acc1 = __builtin_amdgcn_mfma_f32_16x16x32_bf16(ah, r.w7, acc1, 0, 0, 0);
}

__global__ __launch_bounds__(256, 3)
void router_mfma(const float* __restrict__ x,
                 const unsigned short* __restrict__ wsg,
                 float* __restrict__ out)
{
    __shared__ __align__(16) float lgt[32 * 68];       // 8704 B only

    const int tid  = threadIdx.x;
    const int lane = tid & 63;
    const int wid  = tid >> 6;     // 0..3
    const int t0   = blockIdx.x * 32;
    const int c16  = lane & 15;
    const int q    = lane >> 4;
    const int tp   = wid & 1;      // token group of 16
    const int eh   = wid >> 1;     // expert half (g = eh*2 + g2)

    const float* bx = x + (size_t)(t0 + tp * 16 + c16) * DIM + q * 8;
    const unsigned short* bw = wsg + eh * 2048 + lane * 8;

    f32x4 acc0 = {0.f, 0.f, 0.f, 0.f};
    f32x4 acc1 = {0.f, 0.f, 0.f, 0.f};

    TR A, B;
    load_tile(A, bx, bw, 0);
    load_tile(B, bx, bw, 1);
    for (int t = 0; t < NT; t += 2) {
        compute_tile(A, acc0, acc1);                   // waits A only; B in flight
        if (t + 2 < NT) load_tile(A, bx, bw, t + 2);
        compute_tile(B, acc0, acc1);
        if (t + 3 < NT) load_tile(B, bx, bw, t + 3);
    }

    // ---- epilogue: logits -> LDS, softmax + top-2 (32 tokens/block) ----
    // C/D layout (m89-verified): col = lane&15 (expert in group), row = q*4+reg
#pragma unroll
    for (int r = 0; r < 4; ++r) {
        lgt[(tp * 16 + q * 4 + r) * 68 + (eh * 2 + 0) * 16 + c16] = acc0[r];
        lgt[(tp * 16 + q * 4 + r) * 68 + (eh * 2 + 1) * 16 + c16] = acc1[r];
    }
    __syncthreads();

    if (tid < 32) {
        const int tkn = t0 + tid;
        float* row = lgt + tid * 68;
        float m = -3.0e38f;
#pragma unroll
        for (int e4 = 0; e4 < NE; e4 += 4) {
            const float4 v = *(const float4*)(row + e4);
            m = fmaxf(m, fmaxf(fmaxf(v.x, v.y), fmaxf(v.z, v.w)));
        }
        float sum = 0.f, v1 = -3.0e38f, v2 = -3.0e38f;
        int i1 = 0, i2 = 0;
#pragma unroll
        for (int e4 = 0; e4 < NE; e4 += 4) {
            const float4 v = *(const float4*)(row + e4);
            sum += __expf(v.x - m) + __expf(v.y - m) + __expf(v.z - m) + __expf(v.w - m);
            const float* pv = &v.x;
#pragma unroll
            for (int j = 0; j < 4; ++j) {              // ascending e => lax.top_k tie-break
                const float p = pv[j];
                const int e = e4 + j;
                if (p > v1)      { v2 = v1; i2 = i1; v1 = p; i1 = e; }
                else if (p > v2) { v2 = p;  i2 = e; }
            }
        }
        const float inv = 1.f / sum;
        row[64] = m; row[65] = inv;
        out[IDX_OFF + (size_t)tkn * 2]     = (float)i1;
        out[IDX_OFF + (size_t)tkn * 2 + 1] = (float)i2;
        out[VAL_OFF + (size_t)tkn * 2]     = __expf(v1 - m) * inv;
        out[VAL_OFF + (size_t)tkn * 2 + 1] = __expf(v2 - m) * inv;
    }
    __syncthreads();

    {   // coalesced probs write: 256 threads x 8 floats = 32 tok x 64 exp
        const int row = tid >> 3;
        const int e8  = (tid & 7) * 8;
        const float m   = lgt[row * 68 + 64];
        const float inv = lgt[row * 68 + 65];
        const float4 v0 = *(const float4*)(lgt + row * 68 + e8);
        const float4 v1 = *(const float4*)(lgt + row * 68 + e8 + 4);
        float4 p0, p1;
        p0.x = __expf(v0.x - m) * inv; p0.y = __expf(v0.y - m) * inv;
        p0.z = __expf(v0.z - m) * inv; p0.w = __expf(v0.w - m) * inv;
        p1.x = __expf(v1.x - m) * inv; p1.y = __expf(v1.y - m) * inv;
        p1.z = __expf(v1.z - m) * inv; p1.w = __expf(v1.w - m) * inv;
        float* dst = out + (size_t)(t0 + row) * NE + e8;
        *(float4*)dst       = p0;
        *(float4*)(dst + 4) = p1;
    }
}

// correctness-only fallback if ws is too small (should not trigger)
__global__ __launch_bounds__(64)
void fallback_kernel(const float* __restrict__ x, const float* __restrict__ W,
                     float* __restrict__ out) {
    const int tk = blockIdx.x * 64 + threadIdx.x;
    const float* xr = x + (size_t)tk * DIM;
    float lg[NE];
    float m = -3.0e38f;
    for (int e = 0; e < NE; ++e) {
        const float* wr = W + (size_t)e * DIM;
        float s = 0.f;
        for (int d = 0; d < DIM; d += 4) {
            const float4 a = *(const float4*)(xr + d);
            const float4 bb = *(const float4*)(wr + d);
            s += a.x * bb.x + a.y * bb.y + a.z * bb.z + a.w * bb.w;
        }
        lg[e] = s; m = fmaxf(m, s);
    }
    float sum = 0.f;
    for (int e = 0; e < NE; ++e) sum += __expf(lg[e] - m);
    const float inv = 1.f / sum;
    float v1 = -3.0e38f, v2 = -3.0e38f; int i1 = 0, i2 = 0;
    for (int e = 0; e < NE; ++e) {
        const float p = __expf(lg[e] - m) * inv;
        out[(size_t)tk * NE + e] = p;
        if (p > v1)      { v2 = v1; i2 = i1; v1 = p; i1 = e; }
        else if (p > v2) { v2 = p;  i2 = e; }
    }
    out[IDX_OFF + (size_t)tk * 2]     = (float)i1;
    out[IDX_OFF + (size_t)tk * 2 + 1] = (float)i2;
    out[VAL_OFF + (size_t)tk * 2]     = v1;
    out[VAL_OFF + (size_t)tk * 2 + 1] = v2;
}

extern "C" void kernel_launch(void* const* d_in, const int* in_sizes, int n_in,
                              void* d_out, int out_size, void* d_ws, size_t ws_size,
                              hipStream_t stream) {
    const float* x = (const float*)d_in[0];
    const float* W = (const float*)d_in[1];
    float* out = (float*)d_out;
    (void)in_sizes; (void)n_in; (void)out_size;

    if (ws_size >= (size_t)NE * DIM * 2 * 2) {         // 1 MB hi+lo bf16
        wconv_kernel<<<256, 256, 0, stream>>>(W, (unsigned short*)d_ws);
        router_mfma<<<TOK / 32, 256, 0, stream>>>(x, (const unsigned short*)d_ws, out);
    } else {
        fallback_kernel<<<TOK / 64, 64, 0, stream>>>(x, W, out);
    }
}

// Round 5
// 406.349 us; speedup vs baseline: 1.0027x; 1.0027x over previous
//
#include <hip/hip_runtime.h>

// TopKRouter: B=4,S=4096,D=4096,E=64,K=2 (tokens=16384)
// R8: direct-to-register MFMA pipeline (no main-loop LDS, no barriers).
// R9 (this round): register ping-pong depth 2 -> 4 (A,B,C,D).
//   R4 post-mortem: waves/CU is grid-pinned at 8 (2/SIMD; 2048 waves on
//   256 CUs) -- TLP can't rise. Per-wave tile work ~100 SIMD-cyc, so
//   2-deep ILP covers ~400 cyc << ~900 cyc HBM-miss latency on x.
//   Depth-4 -> 48 KB/wave in flight (48 loads, < vmcnt cap 63), ~800 cyc
//   tolerance. launch_bounds(256,2): grid gives only 2 blocks/CU, so no
//   occupancy loss from the higher VGPR cap (~170 used).
//   Harness floor note: timed region includes a 1.07 GB ws re-poison fill
//   (~160us) + ~90us small dispatches; only the router+wconv (~150us) is
//   controllable. Router compute floor ~25us, memory floor ~45-50us.
//   Same numerics as R4/R8 (split-bf16 3-MFMA), epilogue unchanged.

#define TOK 16384
#define DIM 4096
#define NE  64
#define BK  64
#define NT  (DIM / BK)           // 64 K-tiles
#define IDX_OFF (TOK * NE)
#define VAL_OFF (IDX_OFF + TOK * 2)

typedef __attribute__((ext_vector_type(8))) short short8;
typedef __attribute__((ext_vector_type(4))) float f32x4;
union pk8u { unsigned int u[4]; short8 s; };

__device__ __forceinline__ unsigned int pack_hi(float fa, float fb) {
    return __builtin_amdgcn_perm(__float_as_uint(fb), __float_as_uint(fa), 0x07060302u);
}
__device__ __forceinline__ unsigned int pack_lo(float fa, float fb) {
    float la = fa - __uint_as_float(__float_as_uint(fa) & 0xffff0000u);  // exact
    float lb = fb - __uint_as_float(__float_as_uint(fb) & 0xffff0000u);  // exact
    return __builtin_amdgcn_perm(__float_as_uint(lb), __float_as_uint(la), 0x07060302u);
}
__device__ __forceinline__ void split8(const float4 v0, const float4 v1,
                                       short8& hi, short8& lo) {
    pk8u h, l;
    h.u[0] = pack_hi(v0.x, v0.y); l.u[0] = pack_lo(v0.x, v0.y);
    h.u[1] = pack_hi(v0.z, v0.w); l.u[1] = pack_lo(v0.z, v0.w);
    h.u[2] = pack_hi(v1.x, v1.y); l.u[2] = pack_lo(v1.x, v1.y);
    h.u[3] = pack_hi(v1.z, v1.w); l.u[3] = pack_lo(v1.z, v1.w);
    hi = h.s; lo = l.s;
}

// W -> fragment-major packed bf16 hi/lo in ws. (unchanged from R4; verified)
// Unit layout: ws unit index r = t*16 + (c*8 + g*2 + h); within unit:
// lane l (0..63), 8 bf16 = W[e = g*16 + (l&15)][t*64 + c*32 + (l>>4)*8 + j]
__global__ __launch_bounds__(256)
void wconv_kernel(const float* __restrict__ W, unsigned short* __restrict__ ws) {
    const int gid = blockIdx.x * 256 + threadIdx.x;   // 0..65535
    const int l = gid & 63;
    const int r = gid >> 6;
    const int h = r & 1;
    const int g = (r >> 1) & 3;
    const int c = (r >> 3) & 1;
    const int t = r >> 4;                              // 0..63
    const int e = g * 16 + (l & 15);
    const int k = t * 64 + c * 32 + (l >> 4) * 8;
    const float4 va = *(const float4*)(W + (size_t)e * DIM + k);
    const float4 vb = *(const float4*)(W + (size_t)e * DIM + k + 4);
    pk8u o;
    if (h == 0) {                                      // wave-uniform branch
        o.u[0] = pack_hi(va.x, va.y); o.u[1] = pack_hi(va.z, va.w);
        o.u[2] = pack_hi(vb.x, vb.y); o.u[3] = pack_hi(vb.z, vb.w);
    } else {
        o.u[0] = pack_lo(va.x, va.y); o.u[1] = pack_lo(va.z, va.w);
        o.u[2] = pack_lo(vb.x, vb.y); o.u[3] = pack_lo(vb.z, vb.w);
    }
    ((uint4*)ws)[gid] = *(uint4*)&o.u[0];
}

// Per-tile register buffer. Named fields only (runtime-indexed ext_vector
// arrays go to scratch — guide rule #20).
struct TR {
    float4 x0, x1, x2, x3;                 // 8 fp32 for c=0, 8 for c=1
    short8 w0, w1, w2, w3, w4, w5, w6, w7; // (c,g2,h) B-frags, this wave's eh
};

// bx = x + token_row*DIM + q*8 ; bw = wsg + eh*2048 + lane*8
__device__ __forceinline__ void load_tile(TR& r, const float* bx,
                                          const unsigned short* bw, int t) {
    const float* px = bx + t * BK;
    r.x0 = *(const float4*)(px);            // c=0: k = q*8 .. +4
    r.x1 = *(const float4*)(px + 4);        //      k = q*8+4 .. +8
    r.x2 = *(const float4*)(px + 32);       // c=1
    r.x3 = *(const float4*)(px + 36);
    // unit u = (c*4 + eh*2 + g2)*2 + h ; short offset = t*8192 + u*512
    const unsigned short* pw = bw + (size_t)t * 8192;
    r.w0 = *(const short8*)(pw);            // c0 g2=0 h=0 (hi)
    r.w1 = *(const short8*)(pw + 512);      // c0 g2=0 h=1 (lo)
    r.w2 = *(const short8*)(pw + 1024);     // c0 g2=1 hi
    r.w3 = *(const short8*)(pw + 1536);     // c0 g2=1 lo
    r.w4 = *(const short8*)(pw + 4096);     // c1 g2=0 hi
    r.w5 = *(const short8*)(pw + 4608);     // c1 g2=0 lo
    r.w6 = *(const short8*)(pw + 5120);     // c1 g2=1 hi
    r.w7 = *(const short8*)(pw + 5632);     // c1 g2=1 lo
}

__device__ __forceinline__ void compute_tile(const TR& r, f32x4& acc0, f32x4& acc1) {
    short8 ah, al;
    split8(r.x0, r.x1, ah, al);            // c=0
    acc0 = __builtin_amdgcn_mfma_f32_16x16x32_bf16(ah, r.w0, acc0, 0, 0, 0);
    acc0 = __builtin_amdgcn_mfma_f32_16x16x32_bf16(al, r.w0, acc0, 0, 0, 0);
    acc0 = __builtin_amdgcn_mfma_f32_16x16x32_bf16(ah, r.w1, acc0, 0, 0, 0);
    acc1 = __builtin_amdgcn_mfma_f32_16x16x32_bf16(ah, r.w2, acc1, 0, 0, 0);
    acc1 = __builtin_amdgcn_mfma_f32_16x16x32_bf16(al, r.w2, acc1, 0, 0, 0);
    acc1 = __builtin_amdgcn_mfma_f32_16x16x32_bf16(ah, r.w3, acc1, 0, 0, 0);
    split8(r.x2, r.x3, ah, al);            // c=1
    acc0 = __builtin_amdgcn_mfma_f32_16x16x32_bf16(ah, r.w4, acc0, 0, 0, 0);
    acc0 = __builtin_amdgcn_mfma_f32_16x16x32_bf16(al, r.w4, acc0, 0, 0, 0);
    acc0 = __builtin_amdgcn_mfma_f32_16x16x32_bf16(ah, r.w5, acc0, 0, 0, 0);
    acc1 = __builtin_amdgcn_mfma_f32_16x16x32_bf16(ah, r.w6, acc1, 0, 0, 0);
    acc1 = __builtin_amdgcn_mfma_f32_16x16x32_bf16(al, r.w6, acc1, 0, 0, 0);
    acc1 = __builtin_amdgcn_mfma_f32_16x16x32_bf16(ah, r.w7, acc1, 0, 0, 0);
}

__global__ __launch_bounds__(256, 2)
void router_mfma(const float* __restrict__ x,
                 const unsigned short* __restrict__ wsg,
                 float* __restrict__ out)
{
    __shared__ __align__(16) float lgt[32 * 68];       // 8704 B only

    const int tid  = threadIdx.x;
    const int lane = tid & 63;
    const int wid  = tid >> 6;     // 0..3
    const int t0   = blockIdx.x * 32;
    const int c16  = lane & 15;
    const int q    = lane >> 4;
    const int tp   = wid & 1;      // token group of 16
    const int eh   = wid >> 1;     // expert half (g = eh*2 + g2)

    const float* bx = x + (size_t)(t0 + tp * 16 + c16) * DIM + q * 8;
    const unsigned short* bw = wsg + eh * 2048 + lane * 8;

    f32x4 acc0 = {0.f, 0.f, 0.f, 0.f};
    f32x4 acc1 = {0.f, 0.f, 0.f, 0.f};

    TR A, B, C, D;                                     // 4-deep pipeline
    load_tile(A, bx, bw, 0);
    load_tile(B, bx, bw, 1);
    load_tile(C, bx, bw, 2);
    load_tile(D, bx, bw, 3);
    for (int t = 0; t < NT; t += 4) {
        compute_tile(A, acc0, acc1);                   // waits A; B,C,D in flight
        if (t + 4 < NT) load_tile(A, bx, bw, t + 4);
        compute_tile(B, acc0, acc1);
        if (t + 5 < NT) load_tile(B, bx, bw, t + 5);
        compute_tile(C, acc0, acc1);
        if (t + 6 < NT) load_tile(C, bx, bw, t + 6);
        compute_tile(D, acc0, acc1);
        if (t + 7 < NT) load_tile(D, bx, bw, t + 7);
    }

    // ---- epilogue: logits -> LDS, softmax + top-2 (32 tokens/block) ----
    // C/D layout (m89-verified): col = lane&15 (expert in group), row = q*4+reg
#pragma unroll
    for (int r = 0; r < 4; ++r) {
        lgt[(tp * 16 + q * 4 + r) * 68 + (eh * 2 + 0) * 16 + c16] = acc0[r];
        lgt[(tp * 16 + q * 4 + r) * 68 + (eh * 2 + 1) * 16 + c16] = acc1[r];
    }
    __syncthreads();

    if (tid < 32) {
        const int tkn = t0 + tid;
        float* row = lgt + tid * 68;
        float m = -3.0e38f;
#pragma unroll
        for (int e4 = 0; e4 < NE; e4 += 4) {
            const float4 v = *(const float4*)(row + e4);
            m = fmaxf(m, fmaxf(fmaxf(v.x, v.y), fmaxf(v.z, v.w)));
        }
        float sum = 0.f, v1 = -3.0e38f, v2 = -3.0e38f;
        int i1 = 0, i2 = 0;
#pragma unroll
        for (int e4 = 0; e4 < NE; e4 += 4) {
            const float4 v = *(const float4*)(row + e4);
            sum += __expf(v.x - m) + __expf(v.y - m) + __expf(v.z - m) + __expf(v.w - m);
            const float* pv = &v.x;
#pragma unroll
            for (int j = 0; j < 4; ++j) {              // ascending e => lax.top_k tie-break
                const float p = pv[j];
                const int e = e4 + j;
                if (p > v1)      { v2 = v1; i2 = i1; v1 = p; i1 = e; }
                else if (p > v2) { v2 = p;  i2 = e; }
            }
        }
        const float inv = 1.f / sum;
        row[64] = m; row[65] = inv;
        out[IDX_OFF + (size_t)tkn * 2]     = (float)i1;
        out[IDX_OFF + (size_t)tkn * 2 + 1] = (float)i2;
        out[VAL_OFF + (size_t)tkn * 2]     = __expf(v1 - m) * inv;
        out[VAL_OFF + (size_t)tkn * 2 + 1] = __expf(v2 - m) * inv;
    }
    __syncthreads();

    {   // coalesced probs write: 256 threads x 8 floats = 32 tok x 64 exp
        const int row = tid >> 3;
        const int e8  = (tid & 7) * 8;
        const float m   = lgt[row * 68 + 64];
        const float inv = lgt[row * 68 + 65];
        const float4 v0 = *(const float4*)(lgt + row * 68 + e8);
        const float4 v1 = *(const float4*)(lgt + row * 68 + e8 + 4);
        float4 p0, p1;
        p0.x = __expf(v0.x - m) * inv; p0.y = __expf(v0.y - m) * inv;
        p0.z = __expf(v0.z - m) * inv; p0.w = __expf(v0.w - m) * inv;
        p1.x = __expf(v1.x - m) * inv; p1.y = __expf(v1.y - m) * inv;
        p1.z = __expf(v1.z - m) * inv; p1.w = __expf(v1.w - m) * inv;
        float* dst = out + (size_t)(t0 + row) * NE + e8;
        *(float4*)dst       = p0;
        *(float4*)(dst + 4) = p1;
    }
}

// correctness-only fallback if ws is too small (should not trigger)
__global__ __launch_bounds__(64)
void fallback_kernel(const float* __restrict__ x, const float* __restrict__ W,
                     float* __restrict__ out) {
    const int tk = blockIdx.x * 64 + threadIdx.x;
    const float* xr = x + (size_t)tk * DIM;
    float lg[NE];
    float m = -3.0e38f;
    for (int e = 0; e < NE; ++e) {
        const float* wr = W + (size_t)e * DIM;
        float s = 0.f;
        for (int d = 0; d < DIM; d += 4) {
            const float4 a = *(const float4*)(xr + d);
            const float4 bb = *(const float4*)(wr + d);
            s += a.x * bb.x + a.y * bb.y + a.z * bb.z + a.w * bb.w;
        }
        lg[e] = s; m = fmaxf(m, s);
    }
    float sum = 0.f;
    for (int e = 0; e < NE; ++e) sum += __expf(lg[e] - m);
    const float inv = 1.f / sum;
    float v1 = -3.0e38f, v2 = -3.0e38f; int i1 = 0, i2 = 0;
    for (int e = 0; e < NE; ++e) {
        const float p = __expf(lg[e] - m) * inv;
        out[(size_t)tk * NE + e] = p;
        if (p > v1)      { v2 = v1; i2 = i1; v1 = p; i1 = e; }
        else if (p > v2) { v2 = p;  i2 = e; }
    }
    out[IDX_OFF + (size_t)tk * 2]     = (float)i1;
    out[IDX_OFF + (size_t)tk * 2 + 1] = (float)i2;
    out[VAL_OFF + (size_t)tk * 2]     = v1;
    out[VAL_OFF + (size_t)tk * 2 + 1] = v2;
}

extern "C" void kernel_launch(void* const* d_in, const int* in_sizes, int n_in,
                              void* d_out, int out_size, void* d_ws, size_t ws_size,
                              hipStream_t stream) {
    const float* x = (const float*)d_in[0];
    const float* W = (const float*)d_in[1];
    float* out = (float*)d_out;
    (void)in_sizes; (void)n_in; (void)out_size;

    if (ws_size >= (size_t)NE * DIM * 2 * 2) {         // 1 MB hi+lo bf16
        wconv_kernel<<<256, 256, 0, stream>>>(W, (unsigned short*)d_ws);
        router_mfma<<<TOK / 32, 256, 0, stream>>>(x, (const unsigned short*)d_ws, out);
    } else {
        fallback_kernel<<<TOK / 64, 64, 0, stream>>>(x, W, out);
    }
}